// Round 1
// baseline (596.775 us; speedup 1.0000x reference)
//
#include <hip/hip_runtime.h>
#include <math.h>

#define N_NODES 50000
#define N_EDGES 800000
#define N_GRAPHS 512

constexpr int SCAN_BLOCKS = (N_NODES + 255) / 256;  // 196

// ---------------- degree histogram over dst ----------------
__global__ void hist_dst(const int* __restrict__ dst, int* __restrict__ cnt) {
    int i = blockIdx.x * blockDim.x + threadIdx.x;
    if (i < N_EDGES) atomicAdd(&cnt[dst[i]], 1);
}

// ---------------- deg_inv_sqrt ----------------
__global__ void compute_dis(const int* __restrict__ cnt, float* __restrict__ dis) {
    int i = blockIdx.x * blockDim.x + threadIdx.x;
    if (i < N_NODES) dis[i] = 1.0f / sqrtf((float)cnt[i] + 1.0f);
}

// ---------------- block-wide exclusive scan helper (256 threads) ----------------
__device__ __forceinline__ int block_exscan(int val, int* lds, int tid) {
    lds[tid] = val;
    __syncthreads();
#pragma unroll
    for (int off = 1; off < 256; off <<= 1) {
        int t = (tid >= off) ? lds[tid - off] : 0;
        __syncthreads();
        lds[tid] += t;
        __syncthreads();
    }
    return lds[tid] - val;  // exclusive prefix
}

__global__ void scan_partial(const int* __restrict__ cnt, int* __restrict__ rowptr,
                             int* __restrict__ partial) {
    __shared__ int lds[256];
    int tid = threadIdx.x;
    int i = blockIdx.x * 256 + tid;
    int v = (i < N_NODES) ? cnt[i] : 0;
    int ex = block_exscan(v, lds, tid);
    if (i < N_NODES) rowptr[i] = ex;
    if (tid == 255) partial[blockIdx.x] = ex + v;
}

__global__ void scan_sums(int* __restrict__ partial) {
    __shared__ int lds[256];
    int tid = threadIdx.x;
    int v = (tid < SCAN_BLOCKS) ? partial[tid] : 0;
    int ex = block_exscan(v, lds, tid);
    if (tid < SCAN_BLOCKS) partial[tid] = ex;
}

__global__ void scan_add(int* __restrict__ rowptr, int* __restrict__ cursor,
                         const int* __restrict__ partial) {
    int i = blockIdx.x * 256 + threadIdx.x;
    if (i < N_NODES) {
        int r = rowptr[i] + partial[blockIdx.x];
        rowptr[i] = r;
        cursor[i] = r;
    }
    if (blockIdx.x == 0 && threadIdx.x == 0) rowptr[N_NODES] = N_EDGES;
}

// ---------------- CSR fill (bin edges by dst) ----------------
__global__ void csr_fill(const int* __restrict__ src, const int* __restrict__ dst,
                         const float* __restrict__ dis, int* __restrict__ cursor,
                         int* __restrict__ col, float* __restrict__ vsrc) {
    int e = blockIdx.x * blockDim.x + threadIdx.x;
    if (e < N_EDGES) {
        int d = dst[e], s = src[e];
        int pos = atomicAdd(&cursor[d], 1);
        col[pos] = s;
        vsrc[pos] = dis[s];
    }
}

// ---------------- f32 tiled GEMM: C[M,N] = A[M,K] @ W[K,N] ----------------
// BM=128 rows/block, 256 threads as 16x16, micro-tile 8 x (N/16).
template <int N, int K>
__global__ __launch_bounds__(256) void gemm_f32(const float* __restrict__ A,
                                                const float* __restrict__ W,
                                                float* __restrict__ C, int M) {
    constexpr int BM = 128;
    constexpr int BK = 32;
    constexpr int TN = N / 16;  // 8 (N=128) or 4 (N=64)
    __shared__ float As[BM][BK + 1];
    __shared__ float Ws[BK][N + 4];
    int tid = threadIdx.x;
    int row0 = blockIdx.x * BM;
    int ty = tid >> 4;  // 0..15 -> rows ty*8 .. ty*8+7
    int tx = tid & 15;  // 0..15 -> cols tx + j*16

    float acc[8][TN];
#pragma unroll
    for (int i = 0; i < 8; i++)
#pragma unroll
        for (int j = 0; j < TN; j++) acc[i][j] = 0.f;

    for (int k0 = 0; k0 < K; k0 += BK) {
        // stage A tile: BM x BK floats = 1024 float4, 4 per thread
#pragma unroll
        for (int t = 0; t < (BM * BK) / (256 * 4); t++) {
            int idx = tid + t * 256;
            int r = idx >> 3;           // BK/4 = 8 float4 per row
            int c = (idx & 7) << 2;
            float4 v = make_float4(0.f, 0.f, 0.f, 0.f);
            int gr = row0 + r;
            if (gr < M) v = *reinterpret_cast<const float4*>(A + (size_t)gr * K + k0 + c);
            As[r][c] = v.x; As[r][c + 1] = v.y; As[r][c + 2] = v.z; As[r][c + 3] = v.w;
        }
        // stage W tile: BK x N floats
#pragma unroll
        for (int t = 0; t < (BK * N) / (256 * 4); t++) {
            int idx = tid + t * 256;
            int r = idx / (N / 4);
            int c = (idx % (N / 4)) << 2;
            float4 v = *reinterpret_cast<const float4*>(W + (size_t)(k0 + r) * N + c);
            Ws[r][c] = v.x; Ws[r][c + 1] = v.y; Ws[r][c + 2] = v.z; Ws[r][c + 3] = v.w;
        }
        __syncthreads();
#pragma unroll
        for (int k = 0; k < BK; k++) {
            float a[8], w[TN];
#pragma unroll
            for (int i = 0; i < 8; i++) a[i] = As[ty * 8 + i][k];
#pragma unroll
            for (int j = 0; j < TN; j++) w[j] = Ws[k][tx + j * 16];
#pragma unroll
            for (int i = 0; i < 8; i++)
#pragma unroll
                for (int j = 0; j < TN; j++) acc[i][j] = fmaf(a[i], w[j], acc[i][j]);
        }
        __syncthreads();
    }
#pragma unroll
    for (int i = 0; i < 8; i++) {
        int gr = row0 + ty * 8 + i;
        if (gr < M) {
#pragma unroll
            for (int j = 0; j < TN; j++) C[(size_t)gr * N + tx + j * 16] = acc[i][j];
        }
    }
}

// ---------------- propagate: out = dis[w]*sum_{e in row} vsrc*h[col] + dis^2*h[w] + b ----------------
// one wave per node; F=128 -> 2 floats/lane, F=64 -> 1 float/lane
template <int F, bool RELU>
__global__ __launch_bounds__(256) void propagate(const float* __restrict__ h,
                                                 const int* __restrict__ rowptr,
                                                 const int* __restrict__ col,
                                                 const float* __restrict__ vsrc,
                                                 const float* __restrict__ dis,
                                                 const float* __restrict__ bias,
                                                 float* __restrict__ out) {
    int w = (blockIdx.x * blockDim.x + threadIdx.x) >> 6;
    int lane = threadIdx.x & 63;
    if (w >= N_NODES) return;
    int s = rowptr[w], e = rowptr[w + 1];
    float acc0 = 0.f, acc1 = 0.f;
    for (int i = s; i < e; i++) {
        int c = col[i];
        float v = vsrc[i];
        acc0 = fmaf(v, h[(size_t)c * F + lane], acc0);
        if (F == 128) acc1 = fmaf(v, h[(size_t)c * F + 64 + lane], acc1);
    }
    float di = dis[w];
    float selfw = di * di;
    float o0 = acc0 * di + selfw * h[(size_t)w * F + lane] + bias[lane];
    if (RELU) o0 = fmaxf(o0, 0.f);
    out[(size_t)w * F + lane] = o0;
    if (F == 128) {
        float o1 = acc1 * di + selfw * h[(size_t)w * F + 64 + lane] + bias[64 + lane];
        if (RELU) o1 = fmaxf(o1, 0.f);
        out[(size_t)w * F + 64 + lane] = o1;
    }
}

// ---------------- scatter-mean pooling (batch is sorted) ----------------
__global__ void pool_kernel(const float* __restrict__ z, const int* __restrict__ batch,
                            float* __restrict__ agg) {
    int g = (blockIdx.x * blockDim.x + threadIdx.x) >> 6;
    int lane = threadIdx.x & 63;
    if (g >= N_GRAPHS) return;
    int l = 0, h = N_NODES;
    while (l < h) { int m = (l + h) >> 1; if (batch[m] < g) l = m + 1; else h = m; }
    int s = l;
    h = N_NODES;
    while (l < h) { int m = (l + h) >> 1; if (batch[m] < g + 1) l = m + 1; else h = m; }
    int e = l;
    float acc = 0.f;
    for (int i = s; i < e; i++) acc += z[(size_t)i * 64 + lane];
    agg[(size_t)g * 64 + lane] = acc / fmaxf((float)(e - s), 1.0f);
}

extern "C" void kernel_launch(void* const* d_in, const int* in_sizes, int n_in,
                              void* d_out, int out_size, void* d_ws, size_t ws_size,
                              hipStream_t stream) {
    const float* x   = (const float*)d_in[0];
    const int* eidx  = (const int*)d_in[1];
    const int* batch = (const int*)d_in[2];
    const float* W1  = (const float*)d_in[3];
    const float* b1  = (const float*)d_in[4];
    const float* W2  = (const float*)d_in[5];
    const float* b2  = (const float*)d_in[6];
    const float* W3  = (const float*)d_in[7];
    const float* b3  = (const float*)d_in[8];
    const float* W4  = (const float*)d_in[9];
    const float* b4  = (const float*)d_in[10];

    const int* src = eidx;            // edge_index[0]
    const int* dst = eidx + N_EDGES;  // edge_index[1]

    float* out_xhat = (float*)d_out;
    float* out_z    = out_xhat + (size_t)N_NODES * 128;
    float* out_agg  = out_z + (size_t)N_NODES * 64;

    // workspace layout
    float* t0    = (float*)d_ws;                        // 50000*128 f32
    float* t1    = t0 + (size_t)N_NODES * 128;          // 50000*128 f32
    int* deg     = (int*)(t1 + (size_t)N_NODES * 128);  // 50000
    float* dis   = (float*)(deg + N_NODES);             // 50000
    int* rowptr  = (int*)(dis + N_NODES);               // 50001 (+pad)
    int* cursor  = rowptr + (N_NODES + 8);              // 50000
    int* partial = cursor + N_NODES;                    // 256
    int* col     = partial + 256;                       // 800000
    float* vsrc  = (float*)(col + N_EDGES);             // 800000

    hipMemsetAsync(deg, 0, N_NODES * sizeof(int), stream);
    hist_dst<<<(N_EDGES + 255) / 256, 256, 0, stream>>>(dst, deg);
    compute_dis<<<SCAN_BLOCKS, 256, 0, stream>>>(deg, dis);
    scan_partial<<<SCAN_BLOCKS, 256, 0, stream>>>(deg, rowptr, partial);
    scan_sums<<<1, 256, 0, stream>>>(partial);
    scan_add<<<SCAN_BLOCKS, 256, 0, stream>>>(rowptr, cursor, partial);
    csr_fill<<<(N_EDGES + 255) / 256, 256, 0, stream>>>(src, dst, dis, cursor, col, vsrc);

    const int GEMM_GRID = (N_NODES + 127) / 128;  // 391
    const int PROP_GRID = (N_NODES + 3) / 4;      // 12500 (4 waves/block)

    // encoder layer 1: h = relu(gcn(x, W1, b1))
    gemm_f32<128, 128><<<GEMM_GRID, 256, 0, stream>>>(x, W1, t0, N_NODES);
    propagate<128, true><<<PROP_GRID, 256, 0, stream>>>(t0, rowptr, col, vsrc, dis, b1, t1);
    // encoder layer 2: z = gcn(h, W2, b2)
    gemm_f32<64, 128><<<GEMM_GRID, 256, 0, stream>>>(t1, W2, t0, N_NODES);
    propagate<64, false><<<PROP_GRID, 256, 0, stream>>>(t0, rowptr, col, vsrc, dis, b2, out_z);
    // pooling
    pool_kernel<<<(N_GRAPHS * 64) / 256, 256, 0, stream>>>(out_z, batch, out_agg);
    // decoder layer 3: h2 = relu(gcn(z, W3, b3))
    gemm_f32<128, 64><<<GEMM_GRID, 256, 0, stream>>>(out_z, W3, t0, N_NODES);
    propagate<128, true><<<PROP_GRID, 256, 0, stream>>>(t0, rowptr, col, vsrc, dis, b3, t1);
    // decoder layer 4: x_hat = gcn(h2, W4, b4)
    gemm_f32<128, 128><<<GEMM_GRID, 256, 0, stream>>>(t1, W4, t0, N_NODES);
    propagate<128, false><<<PROP_GRID, 256, 0, stream>>>(t0, rowptr, col, vsrc, dis, b4, out_xhat);
}

// Round 2
// 450.822 us; speedup vs baseline: 1.3237x; 1.3237x over previous
//
#include <hip/hip_runtime.h>
#include <math.h>

#define N_NODES 50000
#define N_EDGES 800000
#define N_GRAPHS 512

constexpr int SCAN_BLOCKS = (N_NODES + 255) / 256;  // 196

// ---------------- degree histogram over dst ----------------
__global__ void hist_dst(const int* __restrict__ dst, int* __restrict__ cnt) {
    int i = blockIdx.x * blockDim.x + threadIdx.x;
    if (i < N_EDGES) atomicAdd(&cnt[dst[i]], 1);
}

// ---------------- deg_inv_sqrt ----------------
__global__ void compute_dis(const int* __restrict__ cnt, float* __restrict__ dis) {
    int i = blockIdx.x * blockDim.x + threadIdx.x;
    if (i < N_NODES) dis[i] = 1.0f / sqrtf((float)cnt[i] + 1.0f);
}

// ---------------- block-wide exclusive scan helper (256 threads) ----------------
__device__ __forceinline__ int block_exscan(int val, int* lds, int tid) {
    lds[tid] = val;
    __syncthreads();
#pragma unroll
    for (int off = 1; off < 256; off <<= 1) {
        int t = (tid >= off) ? lds[tid - off] : 0;
        __syncthreads();
        lds[tid] += t;
        __syncthreads();
    }
    return lds[tid] - val;  // exclusive prefix
}

__global__ void scan_partial(const int* __restrict__ cnt, int* __restrict__ rowptr,
                             int* __restrict__ partial) {
    __shared__ int lds[256];
    int tid = threadIdx.x;
    int i = blockIdx.x * 256 + tid;
    int v = (i < N_NODES) ? cnt[i] : 0;
    int ex = block_exscan(v, lds, tid);
    if (i < N_NODES) rowptr[i] = ex;
    if (tid == 255) partial[blockIdx.x] = ex + v;
}

__global__ void scan_sums(int* __restrict__ partial) {
    __shared__ int lds[256];
    int tid = threadIdx.x;
    int v = (tid < SCAN_BLOCKS) ? partial[tid] : 0;
    int ex = block_exscan(v, lds, tid);
    if (tid < SCAN_BLOCKS) partial[tid] = ex;
}

__global__ void scan_add(int* __restrict__ rowptr, int* __restrict__ cursor,
                         const int* __restrict__ partial) {
    int i = blockIdx.x * 256 + threadIdx.x;
    if (i < N_NODES) {
        int r = rowptr[i] + partial[blockIdx.x];
        rowptr[i] = r;
        cursor[i] = r;
    }
    if (blockIdx.x == 0 && threadIdx.x == 0) rowptr[N_NODES] = N_EDGES;
}

// ---------------- CSR fill (bin edges by dst) ----------------
__global__ void csr_fill(const int* __restrict__ src, const int* __restrict__ dst,
                         const float* __restrict__ dis, int* __restrict__ cursor,
                         int* __restrict__ col, float* __restrict__ vsrc) {
    int e = blockIdx.x * blockDim.x + threadIdx.x;
    if (e < N_EDGES) {
        int d = dst[e], s = src[e];
        int pos = atomicAdd(&cursor[d], 1);
        col[pos] = s;
        vsrc[pos] = dis[s];
    }
}

// ---------------- f32 tiled GEMM: C[M,N] = A[M,K] @ W[K,N] (+bias, relu) ----------------
template <int N, int K, bool BIAS, bool RELU>
__global__ __launch_bounds__(256) void gemm_f32(const float* __restrict__ A,
                                                const float* __restrict__ W,
                                                const float* __restrict__ bias,
                                                float* __restrict__ C, int M) {
    constexpr int BM = 128;
    constexpr int BK = 32;
    constexpr int TN = N / 16;  // 8 (N=128) or 4 (N=64)
    __shared__ float As[BM][BK + 1];
    __shared__ float Ws[BK][N + 4];
    int tid = threadIdx.x;
    int row0 = blockIdx.x * BM;
    int ty = tid >> 4;  // 0..15 -> rows ty*8 .. ty*8+7
    int tx = tid & 15;  // 0..15 -> cols tx + j*16

    float acc[8][TN];
#pragma unroll
    for (int i = 0; i < 8; i++)
#pragma unroll
        for (int j = 0; j < TN; j++) acc[i][j] = 0.f;

    for (int k0 = 0; k0 < K; k0 += BK) {
#pragma unroll
        for (int t = 0; t < (BM * BK) / (256 * 4); t++) {
            int idx = tid + t * 256;
            int r = idx >> 3;
            int c = (idx & 7) << 2;
            float4 v = make_float4(0.f, 0.f, 0.f, 0.f);
            int gr = row0 + r;
            if (gr < M) v = *reinterpret_cast<const float4*>(A + (size_t)gr * K + k0 + c);
            As[r][c] = v.x; As[r][c + 1] = v.y; As[r][c + 2] = v.z; As[r][c + 3] = v.w;
        }
#pragma unroll
        for (int t = 0; t < (BK * N) / (256 * 4); t++) {
            int idx = tid + t * 256;
            int r = idx / (N / 4);
            int c = (idx % (N / 4)) << 2;
            float4 v = *reinterpret_cast<const float4*>(W + (size_t)(k0 + r) * N + c);
            Ws[r][c] = v.x; Ws[r][c + 1] = v.y; Ws[r][c + 2] = v.z; Ws[r][c + 3] = v.w;
        }
        __syncthreads();
#pragma unroll
        for (int k = 0; k < BK; k++) {
            float a[8], w[TN];
#pragma unroll
            for (int i = 0; i < 8; i++) a[i] = As[ty * 8 + i][k];
#pragma unroll
            for (int j = 0; j < TN; j++) w[j] = Ws[k][tx + j * 16];
#pragma unroll
            for (int i = 0; i < 8; i++)
#pragma unroll
                for (int j = 0; j < TN; j++) acc[i][j] = fmaf(a[i], w[j], acc[i][j]);
        }
        __syncthreads();
    }
    float bv[TN];
#pragma unroll
    for (int j = 0; j < TN; j++) bv[j] = BIAS ? bias[tx + j * 16] : 0.f;
#pragma unroll
    for (int i = 0; i < 8; i++) {
        int gr = row0 + ty * 8 + i;
        if (gr < M) {
#pragma unroll
            for (int j = 0; j < TN; j++) {
                float v = acc[i][j] + bv[j];
                if (RELU) v = fmaxf(v, 0.f);
                C[(size_t)gr * N + tx + j * 16] = v;
            }
        }
    }
}

// ---------------- propagate: out = dis[w]*sum_{e in row} vsrc*h[col] + dis^2*h[w] (+b, relu) ----
// one wave per node; F=128 -> float2/lane, F=64 -> float/lane. 4x edge unroll for MLP.
template <int F, bool RELU, bool BIAS>
__global__ __launch_bounds__(256) void propagate(const float* __restrict__ h,
                                                 const int* __restrict__ rowptr,
                                                 const int* __restrict__ col,
                                                 const float* __restrict__ vsrc,
                                                 const float* __restrict__ dis,
                                                 const float* __restrict__ bias,
                                                 float* __restrict__ out) {
    int w = (blockIdx.x * blockDim.x + threadIdx.x) >> 6;
    int lane = threadIdx.x & 63;
    if (w >= N_NODES) return;
    int s = rowptr[w], e = rowptr[w + 1];
    float di = dis[w];
    float selfw = di * di;

    if (F == 128) {
        float2 accA = make_float2(0.f, 0.f);
        float2 accB = make_float2(0.f, 0.f);
        int i = s;
        for (; i + 4 <= e; i += 4) {
            int c0 = col[i], c1 = col[i + 1], c2 = col[i + 2], c3 = col[i + 3];
            float v0 = vsrc[i], v1 = vsrc[i + 1], v2 = vsrc[i + 2], v3 = vsrc[i + 3];
            float2 h0 = reinterpret_cast<const float2*>(h + (size_t)c0 * 128)[lane];
            float2 h1 = reinterpret_cast<const float2*>(h + (size_t)c1 * 128)[lane];
            float2 h2 = reinterpret_cast<const float2*>(h + (size_t)c2 * 128)[lane];
            float2 h3 = reinterpret_cast<const float2*>(h + (size_t)c3 * 128)[lane];
            accA.x = fmaf(v0, h0.x, accA.x); accA.y = fmaf(v0, h0.y, accA.y);
            accB.x = fmaf(v1, h1.x, accB.x); accB.y = fmaf(v1, h1.y, accB.y);
            accA.x = fmaf(v2, h2.x, accA.x); accA.y = fmaf(v2, h2.y, accA.y);
            accB.x = fmaf(v3, h3.x, accB.x); accB.y = fmaf(v3, h3.y, accB.y);
        }
        for (; i < e; i++) {
            int c = col[i];
            float v = vsrc[i];
            float2 hv = reinterpret_cast<const float2*>(h + (size_t)c * 128)[lane];
            accA.x = fmaf(v, hv.x, accA.x); accA.y = fmaf(v, hv.y, accA.y);
        }
        float2 selfv = reinterpret_cast<const float2*>(h + (size_t)w * 128)[lane];
        float2 o;
        o.x = (accA.x + accB.x) * di + selfw * selfv.x;
        o.y = (accA.y + accB.y) * di + selfw * selfv.y;
        if (BIAS) {
            float2 bv = reinterpret_cast<const float2*>(bias)[lane];
            o.x += bv.x; o.y += bv.y;
        }
        if (RELU) { o.x = fmaxf(o.x, 0.f); o.y = fmaxf(o.y, 0.f); }
        reinterpret_cast<float2*>(out + (size_t)w * 128)[lane] = o;
    } else {
        float accA = 0.f, accB = 0.f;
        int i = s;
        for (; i + 4 <= e; i += 4) {
            int c0 = col[i], c1 = col[i + 1], c2 = col[i + 2], c3 = col[i + 3];
            float v0 = vsrc[i], v1 = vsrc[i + 1], v2 = vsrc[i + 2], v3 = vsrc[i + 3];
            float h0 = h[(size_t)c0 * 64 + lane];
            float h1 = h[(size_t)c1 * 64 + lane];
            float h2 = h[(size_t)c2 * 64 + lane];
            float h3 = h[(size_t)c3 * 64 + lane];
            accA = fmaf(v0, h0, accA);
            accB = fmaf(v1, h1, accB);
            accA = fmaf(v2, h2, accA);
            accB = fmaf(v3, h3, accB);
        }
        for (; i < e; i++) {
            accA = fmaf(vsrc[i], h[(size_t)col[i] * 64 + lane], accA);
        }
        float o = (accA + accB) * di + selfw * h[(size_t)w * 64 + lane];
        if (BIAS) o += bias[lane];
        if (RELU) o = fmaxf(o, 0.f);
        out[(size_t)w * 64 + lane] = o;
    }
}

// ---------------- scatter-mean pooling (batch is sorted) ----------------
__global__ void pool_kernel(const float* __restrict__ z, const int* __restrict__ batch,
                            float* __restrict__ agg) {
    int g = (blockIdx.x * blockDim.x + threadIdx.x) >> 6;
    int lane = threadIdx.x & 63;
    if (g >= N_GRAPHS) return;
    int l = 0, h = N_NODES;
    while (l < h) { int m = (l + h) >> 1; if (batch[m] < g) l = m + 1; else h = m; }
    int s = l;
    h = N_NODES;
    while (l < h) { int m = (l + h) >> 1; if (batch[m] < g + 1) l = m + 1; else h = m; }
    int e = l;
    float acc = 0.f;
    for (int i = s; i < e; i++) acc += z[(size_t)i * 64 + lane];
    agg[(size_t)g * 64 + lane] = acc / fmaxf((float)(e - s), 1.0f);
}

extern "C" void kernel_launch(void* const* d_in, const int* in_sizes, int n_in,
                              void* d_out, int out_size, void* d_ws, size_t ws_size,
                              hipStream_t stream) {
    const float* x   = (const float*)d_in[0];
    const int* eidx  = (const int*)d_in[1];
    const int* batch = (const int*)d_in[2];
    const float* W1  = (const float*)d_in[3];
    const float* b1  = (const float*)d_in[4];
    const float* W2  = (const float*)d_in[5];
    const float* b2  = (const float*)d_in[6];
    const float* W3  = (const float*)d_in[7];
    const float* b3  = (const float*)d_in[8];
    const float* W4  = (const float*)d_in[9];
    const float* b4  = (const float*)d_in[10];

    const int* src = eidx;            // edge_index[0]
    const int* dst = eidx + N_EDGES;  // edge_index[1]

    float* out_xhat = (float*)d_out;
    float* out_z    = out_xhat + (size_t)N_NODES * 128;
    float* out_agg  = out_z + (size_t)N_NODES * 64;

    // workspace layout
    float* t0    = (float*)d_ws;                        // 50000*128 f32
    float* t1    = t0 + (size_t)N_NODES * 128;          // 50000*128 f32
    int* deg     = (int*)(t1 + (size_t)N_NODES * 128);  // 50000
    float* dis   = (float*)(deg + N_NODES);             // 50000
    int* rowptr  = (int*)(dis + N_NODES);               // 50001 (+pad)
    int* cursor  = rowptr + (N_NODES + 8);              // 50000
    int* partial = cursor + N_NODES;                    // 256
    int* col     = partial + 256;                       // 800000
    float* vsrc  = (float*)(col + N_EDGES);             // 800000

    hipMemsetAsync(deg, 0, N_NODES * sizeof(int), stream);
    hist_dst<<<(N_EDGES + 255) / 256, 256, 0, stream>>>(dst, deg);
    compute_dis<<<SCAN_BLOCKS, 256, 0, stream>>>(deg, dis);
    scan_partial<<<SCAN_BLOCKS, 256, 0, stream>>>(deg, rowptr, partial);
    scan_sums<<<1, 256, 0, stream>>>(partial);
    scan_add<<<SCAN_BLOCKS, 256, 0, stream>>>(rowptr, cursor, partial);
    csr_fill<<<(N_EDGES + 255) / 256, 256, 0, stream>>>(src, dst, dis, cursor, col, vsrc);

    const int GEMM_GRID = (N_NODES + 127) / 128;  // 391
    const int PROP_GRID = (N_NODES + 3) / 4;      // 12500 (4 waves/block)

    // L1: h = relu(P x W1 + b1)   [gemm first, propagate fuses bias+relu]
    gemm_f32<128, 128, false, false><<<GEMM_GRID, 256, 0, stream>>>(x, W1, nullptr, t0, N_NODES);
    propagate<128, true, true><<<PROP_GRID, 256, 0, stream>>>(t0, rowptr, col, vsrc, dis, b1, t1);
    // L2: z = P h W2 + b2   [gemm first: propagate at F=64]
    gemm_f32<64, 128, false, false><<<GEMM_GRID, 256, 0, stream>>>(t1, W2, nullptr, t0, N_NODES);
    propagate<64, false, true><<<PROP_GRID, 256, 0, stream>>>(t0, rowptr, col, vsrc, dis, b2, out_z);
    // pooling
    pool_kernel<<<(N_GRAPHS * 64) / 256, 256, 0, stream>>>(out_z, batch, out_agg);
    // L3: h2 = relu((P z) W3 + b3)   [REORDERED: propagate at F=64 first, gemm fuses bias+relu]
    propagate<64, false, false><<<PROP_GRID, 256, 0, stream>>>(out_z, rowptr, col, vsrc, dis, nullptr, t0);
    gemm_f32<128, 64, true, true><<<GEMM_GRID, 256, 0, stream>>>(t0, W3, b3, t1, N_NODES);
    // L4: x_hat = P (h2 W4) + b4
    gemm_f32<128, 128, false, false><<<GEMM_GRID, 256, 0, stream>>>(t1, W4, nullptr, t0, N_NODES);
    propagate<128, false, true><<<PROP_GRID, 256, 0, stream>>>(t0, rowptr, col, vsrc, dis, b4, out_xhat);
}

// Round 3
// 354.945 us; speedup vs baseline: 1.6813x; 1.2701x over previous
//
#include <hip/hip_runtime.h>
#include <math.h>

#define N_NODES 50000
#define N_EDGES 800000
#define N_GRAPHS 512

typedef unsigned short u16;
typedef unsigned int u32;
typedef __attribute__((ext_vector_type(8))) short bf16x8_t;
typedef __attribute__((ext_vector_type(4))) float f32x4_t;

constexpr int SCAN_BLOCKS = (N_NODES + 255) / 256;  // 196

// ---- bf16 helpers (RTNE, finite values only) ----
__device__ __forceinline__ u16 f2bf(float f) {
    u32 u = __builtin_bit_cast(u32, f);
    return (u16)((u + 0x7fffu + ((u >> 16) & 1u)) >> 16);
}
__device__ __forceinline__ float bf2f(u16 s) {
    return __builtin_bit_cast(float, (u32)s << 16);
}
__device__ __forceinline__ float bf_lo(u32 u) { return __builtin_bit_cast(float, u << 16); }
__device__ __forceinline__ float bf_hi(u32 u) { return __builtin_bit_cast(float, u & 0xffff0000u); }

// ---------------- degree histogram over dst ----------------
__global__ void hist_dst(const int* __restrict__ dst, int* __restrict__ cnt) {
    int i = blockIdx.x * blockDim.x + threadIdx.x;
    if (i < N_EDGES) atomicAdd(&cnt[dst[i]], 1);
}

__global__ void compute_dis(const int* __restrict__ cnt, float* __restrict__ dis) {
    int i = blockIdx.x * blockDim.x + threadIdx.x;
    if (i < N_NODES) dis[i] = 1.0f / sqrtf((float)cnt[i] + 1.0f);
}

// ---------------- block-wide exclusive scan ----------------
__device__ __forceinline__ int block_exscan(int val, int* lds, int tid) {
    lds[tid] = val;
    __syncthreads();
#pragma unroll
    for (int off = 1; off < 256; off <<= 1) {
        int t = (tid >= off) ? lds[tid - off] : 0;
        __syncthreads();
        lds[tid] += t;
        __syncthreads();
    }
    return lds[tid] - val;
}

__global__ void scan_partial(const int* __restrict__ cnt, int* __restrict__ rowptr,
                             int* __restrict__ partial) {
    __shared__ int lds[256];
    int tid = threadIdx.x;
    int i = blockIdx.x * 256 + tid;
    int v = (i < N_NODES) ? cnt[i] : 0;
    int ex = block_exscan(v, lds, tid);
    if (i < N_NODES) rowptr[i] = ex;
    if (tid == 255) partial[blockIdx.x] = ex + v;
}

__global__ void scan_sums(int* __restrict__ partial) {
    __shared__ int lds[256];
    int tid = threadIdx.x;
    int v = (tid < SCAN_BLOCKS) ? partial[tid] : 0;
    int ex = block_exscan(v, lds, tid);
    if (tid < SCAN_BLOCKS) partial[tid] = ex;
}

__global__ void scan_add(int* __restrict__ rowptr, int* __restrict__ cursor,
                         const int* __restrict__ partial) {
    int i = blockIdx.x * 256 + threadIdx.x;
    if (i < N_NODES) {
        int r = rowptr[i] + partial[blockIdx.x];
        rowptr[i] = r;
        cursor[i] = r;
    }
    if (blockIdx.x == 0 && threadIdx.x == 0) rowptr[N_NODES] = N_EDGES;
}

__global__ void csr_fill(const int* __restrict__ src, const int* __restrict__ dst,
                         const float* __restrict__ dis, int* __restrict__ cursor,
                         int* __restrict__ col, float* __restrict__ vsrc) {
    int e = blockIdx.x * blockDim.x + threadIdx.x;
    if (e < N_EDGES) {
        int d = dst[e], s = src[e];
        int pos = atomicAdd(&cursor[d], 1);
        col[pos] = s;
        vsrc[pos] = dis[s];
    }
}

// ---------------- conversions ----------------
__global__ void convert_x_bf16(const float* __restrict__ x, u16* __restrict__ xb) {
    int i = blockIdx.x * 256 + threadIdx.x;  // one float4 per thread
    if (i >= (N_NODES * 128) / 4) return;
    float4 v = reinterpret_cast<const float4*>(x)[i];
    u32 lo = (u32)f2bf(v.x) | ((u32)f2bf(v.y) << 16);
    u32 hi = (u32)f2bf(v.z) | ((u32)f2bf(v.w) << 16);
    reinterpret_cast<uint2*>(xb)[i] = make_uint2(lo, hi);
}

// W[K][N] f32 -> Wt[N][K] bf16
__global__ void convert_wT(const float* __restrict__ Wf, u16* __restrict__ Wt, int K, int N) {
    int idx = blockIdx.x * 256 + threadIdx.x;
    if (idx < K * N) {
        int k = idx / N, n = idx % N;
        Wt[n * K + k] = f2bf(Wf[idx]);
    }
}

// ---------------- bf16 MFMA GEMM: C[M,N] = A[M,K] @ Wt[N,K]^T (+bias, relu) ----------------
// one wave per 64x64 output tile; 16x16x32 MFMA; A,Wt row-major bf16; C bf16.
template <int N, int K, bool BIAS, bool RELU>
__global__ __launch_bounds__(256) void gemm_mfma(const u16* __restrict__ A,
                                                 const u16* __restrict__ Wt,
                                                 const float* __restrict__ bias,
                                                 u16* __restrict__ C) {
    constexpr int KB = K / 32;
    constexpr int TN = N / 64;
    constexpr int TM = (N_NODES + 63) / 64;  // 782
    int wave = threadIdx.x >> 6;
    int lane = threadIdx.x & 63;
    int W = blockIdx.x * 4 + wave;
    if (W >= TM * TN) return;
    int tm = W / TN, tn = W % TN;
    int r16 = lane & 15;  // A row-in-frag / B col-in-frag / D col
    int kg = lane >> 4;   // k-group (8 contiguous k each)

    // B fragments (Wt row-major: 8 contiguous k per lane)
    bf16x8_t bf[4][KB];
#pragma unroll
    for (int nr = 0; nr < 4; nr++) {
        int colg = tn * 64 + nr * 16 + r16;
#pragma unroll
        for (int kb = 0; kb < KB; kb++)
            bf[nr][kb] = *reinterpret_cast<const bf16x8_t*>(Wt + (size_t)colg * K + kb * 32 + kg * 8);
    }

    f32x4_t acc[4][4];
#pragma unroll
    for (int mr = 0; mr < 4; mr++)
#pragma unroll
        for (int nr = 0; nr < 4; nr++)
#pragma unroll
            for (int t = 0; t < 4; t++) acc[mr][nr][t] = 0.f;

#pragma unroll
    for (int mr = 0; mr < 4; mr++) {
        int row = tm * 64 + mr * 16 + r16;
        if (row >= N_NODES) row = N_NODES - 1;  // clamp; stores are guarded
        bf16x8_t af[KB];
#pragma unroll
        for (int kb = 0; kb < KB; kb++)
            af[kb] = *reinterpret_cast<const bf16x8_t*>(A + (size_t)row * K + kb * 32 + kg * 8);
#pragma unroll
        for (int kb = 0; kb < KB; kb++)
#pragma unroll
            for (int nr = 0; nr < 4; nr++)
                acc[mr][nr] = __builtin_amdgcn_mfma_f32_16x16x32_bf16(af[kb], bf[nr][kb],
                                                                      acc[mr][nr], 0, 0, 0);
    }

    // epilogue: D lane mapping col=lane&15, row=(lane>>4)*4+r
#pragma unroll
    for (int mr = 0; mr < 4; mr++) {
#pragma unroll
        for (int nr = 0; nr < 4; nr++) {
            int colg = tn * 64 + nr * 16 + r16;
            float bv = BIAS ? bias[colg] : 0.f;
#pragma unroll
            for (int r = 0; r < 4; r++) {
                int row = tm * 64 + mr * 16 + kg * 4 + r;
                if (row < N_NODES) {
                    float v = acc[mr][nr][r] + bv;
                    if (RELU) v = fmaxf(v, 0.f);
                    C[(size_t)row * N + colg] = f2bf(v);
                }
            }
        }
    }
}

// ---------------- propagate (bf16 input): out = dis[w]*sum vsrc*h[col] + dis^2*h[w] (+b, relu) --
template <int F, bool RELU, bool BIAS, bool WF32, bool WBF16>
__global__ __launch_bounds__(256) void propagate_b(const u16* __restrict__ h,
                                                   const int* __restrict__ rowptr,
                                                   const int* __restrict__ col,
                                                   const float* __restrict__ vsrc,
                                                   const float* __restrict__ dis,
                                                   const float* __restrict__ bias,
                                                   float* __restrict__ out_f,
                                                   u16* __restrict__ out_b) {
    int w = (blockIdx.x * blockDim.x + threadIdx.x) >> 6;
    int lane = threadIdx.x & 63;
    if (w >= N_NODES) return;
    int s = rowptr[w], e = rowptr[w + 1];
    float di = dis[w];
    float selfw = di * di;

    if (F == 128) {
        const u32* hw = reinterpret_cast<const u32*>(h);  // 64 u32 per row
        float2 accA = make_float2(0.f, 0.f), accB = make_float2(0.f, 0.f);
        int i = s;
        for (; i + 8 <= e; i += 8) {
            u32 hv[8];
            float vv[8];
#pragma unroll
            for (int j = 0; j < 8; j++) {
                int c = col[i + j];
                hv[j] = hw[(size_t)c * 64 + lane];
                vv[j] = vsrc[i + j];
            }
#pragma unroll
            for (int j = 0; j < 8; j++) {
                float lo = bf_lo(hv[j]), hi = bf_hi(hv[j]);
                if (j & 1) {
                    accB.x = fmaf(vv[j], lo, accB.x);
                    accB.y = fmaf(vv[j], hi, accB.y);
                } else {
                    accA.x = fmaf(vv[j], lo, accA.x);
                    accA.y = fmaf(vv[j], hi, accA.y);
                }
            }
        }
        for (; i < e; i++) {
            int c = col[i];
            float v = vsrc[i];
            u32 u = hw[(size_t)c * 64 + lane];
            accA.x = fmaf(v, bf_lo(u), accA.x);
            accA.y = fmaf(v, bf_hi(u), accA.y);
        }
        u32 su = hw[(size_t)w * 64 + lane];
        float ox = (accA.x + accB.x) * di + selfw * bf_lo(su);
        float oy = (accA.y + accB.y) * di + selfw * bf_hi(su);
        if (BIAS) {
            float2 bv = reinterpret_cast<const float2*>(bias)[lane];
            ox += bv.x;
            oy += bv.y;
        }
        if (RELU) { ox = fmaxf(ox, 0.f); oy = fmaxf(oy, 0.f); }
        if (WF32) {
            float2 o = make_float2(ox, oy);
            reinterpret_cast<float2*>(out_f + (size_t)w * 128)[lane] = o;
        }
        if (WBF16) {
            u32 pk = (u32)f2bf(ox) | ((u32)f2bf(oy) << 16);
            reinterpret_cast<u32*>(out_b)[(size_t)w * 64 + lane] = pk;
        }
    } else {
        float accA = 0.f, accB = 0.f;
        int i = s;
        for (; i + 8 <= e; i += 8) {
            u16 hv[8];
            float vv[8];
#pragma unroll
            for (int j = 0; j < 8; j++) {
                int c = col[i + j];
                hv[j] = h[(size_t)c * 64 + lane];
                vv[j] = vsrc[i + j];
            }
#pragma unroll
            for (int j = 0; j < 8; j++) {
                if (j & 1) accB = fmaf(vv[j], bf2f(hv[j]), accB);
                else       accA = fmaf(vv[j], bf2f(hv[j]), accA);
            }
        }
        for (; i < e; i++) accA = fmaf(vsrc[i], bf2f(h[(size_t)col[i] * 64 + lane]), accA);
        float o = (accA + accB) * di + selfw * bf2f(h[(size_t)w * 64 + lane]);
        if (BIAS) o += bias[lane];
        if (RELU) o = fmaxf(o, 0.f);
        if (WF32) out_f[(size_t)w * 64 + lane] = o;
        if (WBF16) out_b[(size_t)w * 64 + lane] = f2bf(o);
    }
}

// ---------------- scatter-mean pooling (batch sorted, z in f32) ----------------
__global__ void pool_kernel(const float* __restrict__ z, const int* __restrict__ batch,
                            float* __restrict__ agg) {
    int g = (blockIdx.x * blockDim.x + threadIdx.x) >> 6;
    int lane = threadIdx.x & 63;
    if (g >= N_GRAPHS) return;
    int l = 0, h = N_NODES;
    while (l < h) { int m = (l + h) >> 1; if (batch[m] < g) l = m + 1; else h = m; }
    int s = l;
    h = N_NODES;
    while (l < h) { int m = (l + h) >> 1; if (batch[m] < g + 1) l = m + 1; else h = m; }
    int e = l;
    float acc = 0.f;
    for (int i = s; i < e; i++) acc += z[(size_t)i * 64 + lane];
    agg[(size_t)g * 64 + lane] = acc / fmaxf((float)(e - s), 1.0f);
}

extern "C" void kernel_launch(void* const* d_in, const int* in_sizes, int n_in,
                              void* d_out, int out_size, void* d_ws, size_t ws_size,
                              hipStream_t stream) {
    const float* x   = (const float*)d_in[0];
    const int* eidx  = (const int*)d_in[1];
    const int* batch = (const int*)d_in[2];
    const float* W1  = (const float*)d_in[3];
    const float* b1  = (const float*)d_in[4];
    const float* W2  = (const float*)d_in[5];
    const float* b2  = (const float*)d_in[6];
    const float* W3  = (const float*)d_in[7];
    const float* b3  = (const float*)d_in[8];
    const float* W4  = (const float*)d_in[9];
    const float* b4  = (const float*)d_in[10];

    const int* src = eidx;
    const int* dst = eidx + N_EDGES;

    float* out_xhat = (float*)d_out;
    float* out_z    = out_xhat + (size_t)N_NODES * 128;
    float* out_agg  = out_z + (size_t)N_NODES * 64;

    // workspace layout (bytes, 256B-aligned chunks)
    char* p = (char*)d_ws;
    auto alloc = [&](size_t bytes) { char* r = p; p += (bytes + 255) & ~(size_t)255; return r; };
    u16* arena0 = (u16*)alloc((size_t)N_NODES * 128 * 2);  // 12.8 MB
    u16* arena1 = (u16*)alloc((size_t)N_NODES * 128 * 2);  // 12.8 MB
    u16* c1     = (u16*)alloc((size_t)N_NODES * 64 * 2);   // 6.4 MB
    u16* c2     = (u16*)alloc((size_t)N_NODES * 64 * 2);   // 6.4 MB
    u16* wt1    = (u16*)alloc(128 * 128 * 2);
    u16* wt2    = (u16*)alloc(128 * 64 * 2);
    u16* wt3    = (u16*)alloc(64 * 128 * 2);
    u16* wt4    = (u16*)alloc(128 * 128 * 2);
    int* deg    = (int*)alloc(N_NODES * 4);
    float* dis  = (float*)alloc(N_NODES * 4);
    int* rowptr = (int*)alloc((N_NODES + 8) * 4);
    int* cursor = (int*)alloc(N_NODES * 4);
    int* partial= (int*)alloc(256 * 4);
    int* col    = (int*)alloc((size_t)N_EDGES * 4);
    float* vsrc = (float*)alloc((size_t)N_EDGES * 4);

    // graph preprocessing
    hipMemsetAsync(deg, 0, N_NODES * sizeof(int), stream);
    hist_dst<<<(N_EDGES + 255) / 256, 256, 0, stream>>>(dst, deg);
    compute_dis<<<SCAN_BLOCKS, 256, 0, stream>>>(deg, dis);
    scan_partial<<<SCAN_BLOCKS, 256, 0, stream>>>(deg, rowptr, partial);
    scan_sums<<<1, 256, 0, stream>>>(partial);
    scan_add<<<SCAN_BLOCKS, 256, 0, stream>>>(rowptr, cursor, partial);
    csr_fill<<<(N_EDGES + 255) / 256, 256, 0, stream>>>(src, dst, dis, cursor, col, vsrc);

    // conversions
    convert_x_bf16<<<(N_NODES * 128 / 4 + 255) / 256, 256, 0, stream>>>(x, arena0);
    convert_wT<<<(128 * 128 + 255) / 256, 256, 0, stream>>>(W1, wt1, 128, 128);
    convert_wT<<<(128 * 64 + 255) / 256, 256, 0, stream>>>(W2, wt2, 128, 64);
    convert_wT<<<(64 * 128 + 255) / 256, 256, 0, stream>>>(W3, wt3, 64, 128);
    convert_wT<<<(128 * 128 + 255) / 256, 256, 0, stream>>>(W4, wt4, 128, 128);

    const int PROP_GRID = (N_NODES + 3) / 4;  // 12500
    const int G128 = ((N_NODES + 63) / 64 * 2 + 3) / 4;  // 391
    const int G64  = ((N_NODES + 63) / 64 * 1 + 3) / 4;  // 196

    // L1: h1 = relu(P(x W1) + b1)
    gemm_mfma<128, 128, false, false><<<G128, 256, 0, stream>>>(arena0, wt1, nullptr, arena1);
    propagate_b<128, true, true, false, true><<<PROP_GRID, 256, 0, stream>>>(
        arena1, rowptr, col, vsrc, dis, b1, nullptr, arena0);
    // L2: z = P(h1 W2) + b2   (f32 z for output/pool, bf16 copy for L3 gather)
    gemm_mfma<64, 128, false, false><<<G64, 256, 0, stream>>>(arena0, wt2, nullptr, c1);
    propagate_b<64, false, true, true, true><<<PROP_GRID, 256, 0, stream>>>(
        c1, rowptr, col, vsrc, dis, b2, out_z, c2);
    pool_kernel<<<(N_GRAPHS * 64) / 256, 256, 0, stream>>>(out_z, batch, out_agg);
    // L3: h2 = relu((P z) W3 + b3)
    propagate_b<64, false, false, false, true><<<PROP_GRID, 256, 0, stream>>>(
        c2, rowptr, col, vsrc, dis, nullptr, nullptr, c1);
    gemm_mfma<128, 64, true, true><<<G128, 256, 0, stream>>>(c1, wt3, b3, arena1);
    // L4: x_hat = P(h2 W4) + b4
    gemm_mfma<128, 128, false, false><<<G128, 256, 0, stream>>>(arena1, wt4, nullptr, arena0);
    propagate_b<128, false, true, true, false><<<PROP_GRID, 256, 0, stream>>>(
        arena0, rowptr, col, vsrc, dis, b4, out_xhat, nullptr);
}

// Round 4
// 294.719 us; speedup vs baseline: 2.0249x; 1.2043x over previous
//
#include <hip/hip_runtime.h>
#include <hip/hip_fp16.h>
#include <math.h>

#define N_NODES 50000
#define N_EDGES 800000
#define N_GRAPHS 512

typedef unsigned short u16;
typedef unsigned int u32;
typedef __attribute__((ext_vector_type(8))) short bf16x8_t;
typedef __attribute__((ext_vector_type(4))) float f32x4_t;

constexpr int SCAN_BLOCKS = (N_NODES + 255) / 256;  // 196

// ---- bf16 helpers (RTNE, finite values only) ----
__device__ __forceinline__ u16 f2bf(float f) {
    u32 u = __builtin_bit_cast(u32, f);
    return (u16)((u + 0x7fffu + ((u >> 16) & 1u)) >> 16);
}
__device__ __forceinline__ float bf2f(u16 s) {
    return __builtin_bit_cast(float, (u32)s << 16);
}
__device__ __forceinline__ float bf_lo(u32 u) { return __builtin_bit_cast(float, u << 16); }
__device__ __forceinline__ float bf_hi(u32 u) { return __builtin_bit_cast(float, u & 0xffff0000u); }
__device__ __forceinline__ float h2f(u16 h) {
    return __half2float(__builtin_bit_cast(__half, h));
}

// ---------------- degree histogram over dst ----------------
__global__ void hist_dst(const int* __restrict__ dst, int* __restrict__ cnt) {
    int i = blockIdx.x * blockDim.x + threadIdx.x;
    if (i < N_EDGES) atomicAdd(&cnt[dst[i]], 1);
}

__global__ void compute_dis(const int* __restrict__ cnt, float* __restrict__ dis) {
    int i = blockIdx.x * blockDim.x + threadIdx.x;
    if (i < N_NODES) dis[i] = 1.0f / sqrtf((float)cnt[i] + 1.0f);
}

// ---------------- block-wide exclusive scan ----------------
__device__ __forceinline__ int block_exscan(int val, int* lds, int tid) {
    lds[tid] = val;
    __syncthreads();
#pragma unroll
    for (int off = 1; off < 256; off <<= 1) {
        int t = (tid >= off) ? lds[tid - off] : 0;
        __syncthreads();
        lds[tid] += t;
        __syncthreads();
    }
    return lds[tid] - val;
}

__global__ void scan_partial(const int* __restrict__ cnt, int* __restrict__ rowptr,
                             int* __restrict__ partial) {
    __shared__ int lds[256];
    int tid = threadIdx.x;
    int i = blockIdx.x * 256 + tid;
    int v = (i < N_NODES) ? cnt[i] : 0;
    int ex = block_exscan(v, lds, tid);
    if (i < N_NODES) rowptr[i] = ex;
    if (tid == 255) partial[blockIdx.x] = ex + v;
}

__global__ void scan_sums(int* __restrict__ partial) {
    __shared__ int lds[256];
    int tid = threadIdx.x;
    int v = (tid < SCAN_BLOCKS) ? partial[tid] : 0;
    int ex = block_exscan(v, lds, tid);
    if (tid < SCAN_BLOCKS) partial[tid] = ex;
}

__global__ void scan_add(int* __restrict__ rowptr, int* __restrict__ cursor,
                         const int* __restrict__ partial) {
    int i = blockIdx.x * 256 + threadIdx.x;
    if (i < N_NODES) {
        int r = rowptr[i] + partial[blockIdx.x];
        rowptr[i] = r;
        cursor[i] = r;
    }
    if (blockIdx.x == 0 && threadIdx.x == 0) rowptr[N_NODES] = N_EDGES;
}

// ---------------- CSR fill: 4 edges/thread, packed meta (u16 col | fp16 dis[src]) -------------
__global__ void csr_fill(const int* __restrict__ src, const int* __restrict__ dst,
                         const float* __restrict__ dis, int* __restrict__ cursor,
                         u32* __restrict__ meta) {
    int base = blockIdx.x * 1024 + threadIdx.x;
    int d[4], s[4];
    float dv[4];
    bool ok[4];
#pragma unroll
    for (int j = 0; j < 4; j++) {
        int e = base + j * 256;
        ok[j] = e < N_EDGES;
        d[j] = ok[j] ? dst[e] : 0;
        s[j] = ok[j] ? src[e] : 0;
    }
#pragma unroll
    for (int j = 0; j < 4; j++) dv[j] = ok[j] ? dis[s[j]] : 0.f;
    int pos[4];
#pragma unroll
    for (int j = 0; j < 4; j++) pos[j] = ok[j] ? atomicAdd(&cursor[d[j]], 1) : 0;
#pragma unroll
    for (int j = 0; j < 4; j++) {
        if (ok[j]) {
            u16 hb = __builtin_bit_cast(u16, __float2half(dv[j]));
            meta[pos[j]] = (u32)(u16)s[j] | ((u32)hb << 16);
        }
    }
}

// ---------------- conversions ----------------
__global__ void convert_x_bf16(const float* __restrict__ x, u16* __restrict__ xb) {
    int i = blockIdx.x * 256 + threadIdx.x;  // one float4 per thread
    if (i >= (N_NODES * 128) / 4) return;
    float4 v = reinterpret_cast<const float4*>(x)[i];
    u32 lo = (u32)f2bf(v.x) | ((u32)f2bf(v.y) << 16);
    u32 hi = (u32)f2bf(v.z) | ((u32)f2bf(v.w) << 16);
    reinterpret_cast<uint2*>(xb)[i] = make_uint2(lo, hi);
}

// W[K][N] f32 -> Wt[N][K] bf16
__global__ void convert_wT(const float* __restrict__ Wf, u16* __restrict__ Wt, int K, int N) {
    int idx = blockIdx.x * 256 + threadIdx.x;
    if (idx < K * N) {
        int k = idx / N, n = idx % N;
        Wt[n * K + k] = f2bf(Wf[idx]);
    }
}

// ---------------- bf16 MFMA GEMM: C[M,N] = A[M,K] @ Wt[N,K]^T (+bias, relu) ----------------
template <int N, int K, bool BIAS, bool RELU>
__global__ __launch_bounds__(256) void gemm_mfma(const u16* __restrict__ A,
                                                 const u16* __restrict__ Wt,
                                                 const float* __restrict__ bias,
                                                 u16* __restrict__ C) {
    constexpr int KB = K / 32;
    constexpr int TN = N / 64;
    constexpr int TM = (N_NODES + 63) / 64;  // 782
    int wave = threadIdx.x >> 6;
    int lane = threadIdx.x & 63;
    int W = blockIdx.x * 4 + wave;
    if (W >= TM * TN) return;
    int tm = W / TN, tn = W % TN;
    int r16 = lane & 15;
    int kg = lane >> 4;

    bf16x8_t bf[4][KB];
#pragma unroll
    for (int nr = 0; nr < 4; nr++) {
        int colg = tn * 64 + nr * 16 + r16;
#pragma unroll
        for (int kb = 0; kb < KB; kb++)
            bf[nr][kb] = *reinterpret_cast<const bf16x8_t*>(Wt + (size_t)colg * K + kb * 32 + kg * 8);
    }

    f32x4_t acc[4][4];
#pragma unroll
    for (int mr = 0; mr < 4; mr++)
#pragma unroll
        for (int nr = 0; nr < 4; nr++)
#pragma unroll
            for (int t = 0; t < 4; t++) acc[mr][nr][t] = 0.f;

#pragma unroll
    for (int mr = 0; mr < 4; mr++) {
        int row = tm * 64 + mr * 16 + r16;
        if (row >= N_NODES) row = N_NODES - 1;
        bf16x8_t af[KB];
#pragma unroll
        for (int kb = 0; kb < KB; kb++)
            af[kb] = *reinterpret_cast<const bf16x8_t*>(A + (size_t)row * K + kb * 32 + kg * 8);
#pragma unroll
        for (int kb = 0; kb < KB; kb++)
#pragma unroll
            for (int nr = 0; nr < 4; nr++)
                acc[mr][nr] = __builtin_amdgcn_mfma_f32_16x16x32_bf16(af[kb], bf[nr][kb],
                                                                      acc[mr][nr], 0, 0, 0);
    }

#pragma unroll
    for (int mr = 0; mr < 4; mr++) {
#pragma unroll
        for (int nr = 0; nr < 4; nr++) {
            int colg = tn * 64 + nr * 16 + r16;
            float bv = BIAS ? bias[colg] : 0.f;
#pragma unroll
            for (int r = 0; r < 4; r++) {
                int row = tm * 64 + mr * 16 + kg * 4 + r;
                if (row < N_NODES) {
                    float v = acc[mr][nr][r] + bv;
                    if (RELU) v = fmaxf(v, 0.f);
                    C[(size_t)row * N + colg] = f2bf(v);
                }
            }
        }
    }
}

// ---------------- propagate (bf16 h, packed meta) ----------------
template <int F, bool RELU, bool BIAS, bool WF32, bool WBF16>
__global__ __launch_bounds__(256) void propagate_b(const u16* __restrict__ h,
                                                   const int* __restrict__ rowptr,
                                                   const u32* __restrict__ meta,
                                                   const float* __restrict__ dis,
                                                   const float* __restrict__ bias,
                                                   float* __restrict__ out_f,
                                                   u16* __restrict__ out_b) {
    int w = (blockIdx.x * blockDim.x + threadIdx.x) >> 6;
    int lane = threadIdx.x & 63;
    if (w >= N_NODES) return;
    int s = __builtin_amdgcn_readfirstlane(rowptr[w]);
    int e = __builtin_amdgcn_readfirstlane(rowptr[w + 1]);
    float di = dis[w];
    float selfw = di * di;

    if (F == 128) {
        const u32* hw = reinterpret_cast<const u32*>(h);  // 64 u32 per row
        float2 accA = make_float2(0.f, 0.f), accB = make_float2(0.f, 0.f);
        int i = s;
        for (; i + 8 <= e; i += 8) {
            u32 m[8], hv[8];
#pragma unroll
            for (int j = 0; j < 8; j++) m[j] = meta[i + j];
#pragma unroll
            for (int j = 0; j < 8; j++) hv[j] = hw[(size_t)(m[j] & 0xffffu) * 64 + lane];
#pragma unroll
            for (int j = 0; j < 8; j++) {
                float v = h2f((u16)(m[j] >> 16));
                float lo = bf_lo(hv[j]), hi = bf_hi(hv[j]);
                if (j & 1) {
                    accB.x = fmaf(v, lo, accB.x);
                    accB.y = fmaf(v, hi, accB.y);
                } else {
                    accA.x = fmaf(v, lo, accA.x);
                    accA.y = fmaf(v, hi, accA.y);
                }
            }
        }
        for (; i < e; i++) {
            u32 m = meta[i];
            float v = h2f((u16)(m >> 16));
            u32 u = hw[(size_t)(m & 0xffffu) * 64 + lane];
            accA.x = fmaf(v, bf_lo(u), accA.x);
            accA.y = fmaf(v, bf_hi(u), accA.y);
        }
        u32 su = hw[(size_t)w * 64 + lane];
        float ox = (accA.x + accB.x) * di + selfw * bf_lo(su);
        float oy = (accA.y + accB.y) * di + selfw * bf_hi(su);
        if (BIAS) {
            float2 bv = reinterpret_cast<const float2*>(bias)[lane];
            ox += bv.x;
            oy += bv.y;
        }
        if (RELU) { ox = fmaxf(ox, 0.f); oy = fmaxf(oy, 0.f); }
        if (WF32) {
            reinterpret_cast<float2*>(out_f + (size_t)w * 128)[lane] = make_float2(ox, oy);
        }
        if (WBF16) {
            u32 pk = (u32)f2bf(ox) | ((u32)f2bf(oy) << 16);
            reinterpret_cast<u32*>(out_b)[(size_t)w * 64 + lane] = pk;
        }
    } else {
        float accA = 0.f, accB = 0.f;
        int i = s;
        for (; i + 8 <= e; i += 8) {
            u32 m[8];
            u16 hv[8];
#pragma unroll
            for (int j = 0; j < 8; j++) m[j] = meta[i + j];
#pragma unroll
            for (int j = 0; j < 8; j++) hv[j] = h[(size_t)(m[j] & 0xffffu) * 64 + lane];
#pragma unroll
            for (int j = 0; j < 8; j++) {
                float v = h2f((u16)(m[j] >> 16));
                if (j & 1) accB = fmaf(v, bf2f(hv[j]), accB);
                else       accA = fmaf(v, bf2f(hv[j]), accA);
            }
        }
        for (; i < e; i++) {
            u32 m = meta[i];
            accA = fmaf(h2f((u16)(m >> 16)), bf2f(h[(size_t)(m & 0xffffu) * 64 + lane]), accA);
        }
        float o = (accA + accB) * di + selfw * bf2f(h[(size_t)w * 64 + lane]);
        if (BIAS) o += bias[lane];
        if (RELU) o = fmaxf(o, 0.f);
        if (WF32) out_f[(size_t)w * 64 + lane] = o;
        if (WBF16) out_b[(size_t)w * 64 + lane] = f2bf(o);
    }
}

// ---------------- scatter-mean pooling: one block (4 waves) per graph ----------------
__global__ __launch_bounds__(256) void pool_kernel(const float* __restrict__ z,
                                                   const int* __restrict__ batch,
                                                   float* __restrict__ agg) {
    __shared__ float part[3][64];
    int g = blockIdx.x;
    int wave = threadIdx.x >> 6;
    int lane = threadIdx.x & 63;
    int l = 0, h = N_NODES;
    while (l < h) { int m = (l + h) >> 1; if (batch[m] < g) l = m + 1; else h = m; }
    int s = l;
    h = N_NODES;
    while (l < h) { int m = (l + h) >> 1; if (batch[m] < g + 1) l = m + 1; else h = m; }
    int e = l;
    float acc = 0.f;
    for (int i = s + wave; i < e; i += 4) acc += z[(size_t)i * 64 + lane];
    if (wave) part[wave - 1][lane] = acc;
    __syncthreads();
    if (wave == 0) {
        acc += part[0][lane] + part[1][lane] + part[2][lane];
        agg[(size_t)g * 64 + lane] = acc / fmaxf((float)(e - s), 1.0f);
    }
}

extern "C" void kernel_launch(void* const* d_in, const int* in_sizes, int n_in,
                              void* d_out, int out_size, void* d_ws, size_t ws_size,
                              hipStream_t stream) {
    const float* x   = (const float*)d_in[0];
    const int* eidx  = (const int*)d_in[1];
    const int* batch = (const int*)d_in[2];
    const float* W1  = (const float*)d_in[3];
    const float* b1  = (const float*)d_in[4];
    const float* W2  = (const float*)d_in[5];
    const float* b2  = (const float*)d_in[6];
    const float* W3  = (const float*)d_in[7];
    const float* b3  = (const float*)d_in[8];
    const float* W4  = (const float*)d_in[9];
    const float* b4  = (const float*)d_in[10];

    const int* src = eidx;
    const int* dst = eidx + N_EDGES;

    float* out_xhat = (float*)d_out;
    float* out_z    = out_xhat + (size_t)N_NODES * 128;
    float* out_agg  = out_z + (size_t)N_NODES * 64;

    char* p = (char*)d_ws;
    auto alloc = [&](size_t bytes) { char* r = p; p += (bytes + 255) & ~(size_t)255; return r; };
    u16* arena0 = (u16*)alloc((size_t)N_NODES * 128 * 2);
    u16* arena1 = (u16*)alloc((size_t)N_NODES * 128 * 2);
    u16* c1     = (u16*)alloc((size_t)N_NODES * 64 * 2);
    u16* c2     = (u16*)alloc((size_t)N_NODES * 64 * 2);
    u16* wt1    = (u16*)alloc(128 * 128 * 2);
    u16* wt2    = (u16*)alloc(128 * 64 * 2);
    u16* wt3    = (u16*)alloc(64 * 128 * 2);
    u16* wt4    = (u16*)alloc(128 * 128 * 2);
    int* deg    = (int*)alloc(N_NODES * 4);
    float* dis  = (float*)alloc(N_NODES * 4);
    int* rowptr = (int*)alloc((N_NODES + 8) * 4);
    int* cursor = (int*)alloc(N_NODES * 4);
    int* partial= (int*)alloc(256 * 4);
    u32* meta   = (u32*)alloc((size_t)N_EDGES * 4);

    hipMemsetAsync(deg, 0, N_NODES * sizeof(int), stream);
    hist_dst<<<(N_EDGES + 255) / 256, 256, 0, stream>>>(dst, deg);
    compute_dis<<<SCAN_BLOCKS, 256, 0, stream>>>(deg, dis);
    scan_partial<<<SCAN_BLOCKS, 256, 0, stream>>>(deg, rowptr, partial);
    scan_sums<<<1, 256, 0, stream>>>(partial);
    scan_add<<<SCAN_BLOCKS, 256, 0, stream>>>(rowptr, cursor, partial);
    csr_fill<<<(N_EDGES + 1023) / 1024, 256, 0, stream>>>(src, dst, dis, cursor, meta);

    convert_x_bf16<<<(N_NODES * 128 / 4 + 255) / 256, 256, 0, stream>>>(x, arena0);
    convert_wT<<<(128 * 128 + 255) / 256, 256, 0, stream>>>(W1, wt1, 128, 128);
    convert_wT<<<(128 * 64 + 255) / 256, 256, 0, stream>>>(W2, wt2, 128, 64);
    convert_wT<<<(64 * 128 + 255) / 256, 256, 0, stream>>>(W3, wt3, 64, 128);
    convert_wT<<<(128 * 128 + 255) / 256, 256, 0, stream>>>(W4, wt4, 128, 128);

    const int PROP_GRID = (N_NODES + 3) / 4;
    const int G128 = ((N_NODES + 63) / 64 * 2 + 3) / 4;  // 391
    const int G64  = ((N_NODES + 63) / 64 * 1 + 3) / 4;  // 196

    // L1: h1 = relu(P(x W1) + b1)
    gemm_mfma<128, 128, false, false><<<G128, 256, 0, stream>>>(arena0, wt1, nullptr, arena1);
    propagate_b<128, true, true, false, true><<<PROP_GRID, 256, 0, stream>>>(
        arena1, rowptr, meta, dis, b1, nullptr, arena0);
    // L2: z = P(h1 W2) + b2
    gemm_mfma<64, 128, false, false><<<G64, 256, 0, stream>>>(arena0, wt2, nullptr, c1);
    propagate_b<64, false, true, true, true><<<PROP_GRID, 256, 0, stream>>>(
        c1, rowptr, meta, dis, b2, out_z, c2);
    pool_kernel<<<N_GRAPHS, 256, 0, stream>>>(out_z, batch, out_agg);
    // L3: h2 = relu((P z) W3 + b3)
    propagate_b<64, false, false, false, true><<<PROP_GRID, 256, 0, stream>>>(
        c2, rowptr, meta, dis, nullptr, nullptr, c1);
    gemm_mfma<128, 64, true, true><<<G128, 256, 0, stream>>>(c1, wt3, b3, arena1);
    // L4: x_hat = P(h2 W4) + b4
    gemm_mfma<128, 128, false, false><<<G128, 256, 0, stream>>>(arena1, wt4, nullptr, arena0);
    propagate_b<128, false, true, true, false><<<PROP_GRID, 256, 0, stream>>>(
        arena0, rowptr, meta, dis, b4, out_xhat, nullptr);
}